// Round 17
// baseline (269.337 us; speedup 1.0000x reference)
//
#include <hip/hip_runtime.h>
#include <hip/hip_bf16.h>

#define HIDDEN 1024
#define B_SZ 32
#define S_SZ 2048
#define M_TOT (B_SZ * S_SZ)          // 65536 rows
#define MASKED_BIAS -10000.0f

using bf16   = __bf16;
using bf16x4 = __attribute__((ext_vector_type(4))) __bf16;
using bf16x8 = __attribute__((ext_vector_type(8))) __bf16;
using f32x4  = __attribute__((ext_vector_type(4))) float;

__device__ __forceinline__ float tanh_fast(float x) {
    float xc = fminf(fmaxf(x, -15.f), 15.f);
    float e2 = __expf(2.f * xc);
    return (e2 - 1.f) * __frcp_rn(e2 + 1.f);
}

// ===========================================================================
// Kernel 0: fused prep. Block ranges:
//   [0,2048)     : K f32->bf16 grid-stride, NT loads (keep dead f32 out of L3)
//   [2048,2560)  : W_K f32->bf16 (2 MB)
//   [2560,3072)  : hl_plus = h@W_h^T + b_h + b_K + b_cov
// ===========================================================================
#define KCONV_BLKS 2048

__global__ __launch_bounds__(256) void k_prep(
    const float* __restrict__ K,   bf16* __restrict__ Kbf,
    const float* __restrict__ W,   bf16* __restrict__ Wbf,
    const float* __restrict__ h,   const float* __restrict__ W_h,
    const float* __restrict__ b_h, const float* __restrict__ b_K,
    const float* __restrict__ b_cov, float* __restrict__ hl_plus)
{
    const int bid = blockIdx.x;
    const int tid = threadIdx.x;

    if (bid < KCONV_BLKS) {
        const size_t n8     = (size_t)M_TOT * HIDDEN / 8;
        const size_t stride = (size_t)KCONV_BLKS * 256;
        for (size_t i = (size_t)bid * 256 + tid; i < n8; i += stride) {
            const f32x4* p = (const f32x4*)K + i * 2;
            f32x4 a = __builtin_nontemporal_load(p);
            f32x4 b = __builtin_nontemporal_load(p + 1);
            bf16x8 v = { (bf16)a[0], (bf16)a[1], (bf16)a[2], (bf16)a[3],
                         (bf16)b[0], (bf16)b[1], (bf16)b[2], (bf16)b[3] };
            *(bf16x8*)(Kbf + i * 8) = v;
        }
    } else if (bid < KCONV_BLKS + 512) {
        int i = (bid - KCONV_BLKS) * 256 + tid;
        const f32x4* p = (const f32x4*)W + (size_t)i * 2;
        f32x4 a = p[0], b = p[1];
        bf16x8 v = { (bf16)a[0], (bf16)a[1], (bf16)a[2], (bf16)a[3],
                     (bf16)b[0], (bf16)b[1], (bf16)b[2], (bf16)b[3] };
        *(bf16x8*)(Wbf + (size_t)i * 8) = v;
    } else {
        int wv   = (bid - (KCONV_BLKS + 512)) * 4 + (tid >> 6);  // 0..2047
        int lane = tid & 63;
        int b    = wv & 31;
        int g0   = wv >> 5;                                      // 0..63
        const float4* hv = (const float4*)(h + b * HIDDEN);
        float4 ha[4];
#pragma unroll
        for (int i = 0; i < 4; ++i) ha[i] = hv[i * 64 + lane];
#pragma unroll 4
        for (int k = 0; k < 16; ++k) {
            int g = g0 + 64 * k;
            const float4* wv4 = (const float4*)(W_h + (size_t)g * HIDDEN);
            float acc = 0.f;
#pragma unroll
            for (int i = 0; i < 4; ++i) {
                float4 w = wv4[i * 64 + lane];
                acc += ha[i].x * w.x + ha[i].y * w.y +
                       ha[i].z * w.z + ha[i].w * w.w;
            }
#pragma unroll
            for (int off = 32; off; off >>= 1) acc += __shfl_xor(acc, off);
            if (lane == 0)
                hl_plus[b * HIDDEN + g] = acc + b_h[g] + b_K[g] + b_cov[g];
        }
    }
}

// ===========================================================================
// Kernel 2 (best measured): fused GEMM+tanh+dot.
// Tile 256x128, BK=32, 512 threads = 8 waves as 4M x 2N -> wave tile 64x64.
// All staging via global_load_lds from bf16; one __syncthreads per K-tile;
// conflict-free XOR swizzle: LDS[row][chunk c] = global chunk c ^ ((row>>1)&3).
// ===========================================================================
#define NT_N 8

__global__ __launch_bounds__(512, 4) void k_fused9(
    const bf16*  __restrict__ Kbf,      // [65536][1024] bf16
    const bf16*  __restrict__ Bbf,      // [1024][1024] bf16 (W_K)
    const float* __restrict__ hl_plus,
    const float* __restrict__ W_cov,
    const float* __restrict__ cov,
    const float* __restrict__ W_v,
    float* __restrict__ e_part)         // [8][65536]
{
    __shared__ __align__(16) bf16 As[2][256][32];   // 32 KB
    __shared__ __align__(16) bf16 Bs[2][128][32];   // 16 KB
    __shared__ float e_buf[256][2];

    const int tid = threadIdx.x;
    const int bid = blockIdx.x;
    // XCD-bijective swizzle: 2048 blocks, 256/XCD, nt fastest within XCD.
    const int lid = (bid & 7) * 256 + (bid >> 3);
    const int mt  = lid >> 3;            // 256 m-tiles (256 rows)
    const int nt  = lid & 7;             // 8 n-tiles (128 cols)
    const int row0 = mt * 256;
    const int col0 = nt * 128;

    const int w    = tid >> 6;           // wave 0..7
    const int lane = tid & 63;
    const int wm   = w >> 1;             // M-quarter (64 rows)
    const int wn   = w & 1;              // N-half    (64 cols)
    const int lr   = lane & 15;
    const int kb   = lane >> 4;
    const int colA = (kb ^ ((lr >> 1) & 3)) * 8;   // read-side swizzled col

    const int srow = lane >> 2;
    const int gch  = (lane & 3) ^ ((lane >> 3) & 3);
    const bf16* Abase = Kbf + (size_t)(row0 + w * 16 + srow) * HIDDEN + gch * 8;
    const bf16* Bbase = Bbf + (size_t)(col0 + w * 16 + srow) * HIDDEN + gch * 8;

    f32x4 acc[4][4] = {};

#define STAGE(KT, BUF)                                                    \
    __builtin_amdgcn_global_load_lds(                                     \
        (const __attribute__((address_space(1))) void*)(Abase + (KT) * 32),\
        (__attribute__((address_space(3))) void*)&As[BUF][w * 16][0],     \
        16, 0, 0);                                                        \
    __builtin_amdgcn_global_load_lds(                                     \
        (const __attribute__((address_space(1))) void*)                   \
            (Abase + (size_t)128 * HIDDEN + (KT) * 32),                   \
        (__attribute__((address_space(3))) void*)&As[BUF][128 + w * 16][0],\
        16, 0, 0);                                                        \
    __builtin_amdgcn_global_load_lds(                                     \
        (const __attribute__((address_space(1))) void*)(Bbase + (KT) * 32),\
        (__attribute__((address_space(3))) void*)&Bs[BUF][w * 16][0],     \
        16, 0, 0);

#define TILE_COMPUTE(BUF)                                                 \
    {                                                                     \
        bf16x8 afr[4], bfr[4];                                            \
        _Pragma("unroll") for (int j = 0; j < 4; ++j)                     \
            afr[j] = *(const bf16x8*)                                     \
                &As[BUF][wm * 64 + j * 16 + lr][colA];                    \
        _Pragma("unroll") for (int n = 0; n < 4; ++n)                     \
            bfr[n] = *(const bf16x8*)&Bs[BUF][wn * 64 + n * 16 + lr][colA];\
        __builtin_amdgcn_s_setprio(1);                                    \
        _Pragma("unroll") for (int j = 0; j < 4; ++j)                     \
            _Pragma("unroll") for (int n = 0; n < 4; ++n)                 \
                acc[j][n] = __builtin_amdgcn_mfma_f32_16x16x32_bf16(      \
                    afr[j], bfr[n], acc[j][n], 0, 0, 0);                  \
        __builtin_amdgcn_s_setprio(0);                                    \
    }

    STAGE(0, 0)
    __syncthreads();

    for (int i = 0; i < 15; ++i) {
        const int t = i * 2;
        STAGE(t + 1, 1)
        TILE_COMPUTE(0)
        __syncthreads();
        STAGE(t + 2, 0)
        TILE_COMPUTE(1)
        __syncthreads();
    }
    STAGE(31, 1)
    TILE_COMPUTE(0)
    __syncthreads();
    TILE_COMPUTE(1)

    // ------------------- epilogue: tanh + dot(W_v) reduction ----------------
    const int bidx = row0 >> 11;
    float hlv[4], wcv[4], wvv[4];
#pragma unroll
    for (int n = 0; n < 4; ++n) {
        int g = col0 + wn * 64 + n * 16 + lr;
        hlv[n] = hl_plus[bidx * HIDDEN + g];
        wcv[n] = W_cov[g];
        wvv[n] = W_v[g];
    }
#pragma unroll
    for (int j = 0; j < 4; ++j) {
#pragma unroll
        for (int i = 0; i < 4; ++i) {
            int rloc = wm * 64 + j * 16 + kb * 4 + i;
            float cv = cov[row0 + rloc];
            float ep = 0.f;
#pragma unroll
            for (int n = 0; n < 4; ++n) {
                float arg = acc[j][n][i] + hlv[n] + cv * wcv[n];
                ep += tanh_fast(arg) * wvv[n];
            }
            ep += __shfl_xor(ep, 1);
            ep += __shfl_xor(ep, 2);
            ep += __shfl_xor(ep, 4);
            ep += __shfl_xor(ep, 8);
            if (lr == 0) e_buf[rloc][wn] = ep;
        }
    }
    __syncthreads();
    if (tid < 256)
        e_part[(size_t)nt * M_TOT + row0 + tid] = e_buf[tid][0] + e_buf[tid][1];

#undef STAGE
#undef TILE_COMPUTE
}

// ===========================================================================
// Kernel 3 (R17): fused softmax + context partials. grid (16, 32).
// Every block redundantly computes batch b's softmax from e_part (64 KB,
// L2-hit) into LDS, then does its 128-row ctx chunk from LDS a-values.
// Block sc==0 also writes a_out and cov_out.
// ===========================================================================
__global__ __launch_bounds__(256) void k_softctx(
    const float* __restrict__ e_part, const float* __restrict__ mask,
    const float* __restrict__ cov, const float* __restrict__ b_v,
    const bf16* __restrict__ Kbf,
    float* __restrict__ a_out, float* __restrict__ cov_out,
    float* __restrict__ part_out)
{
    __shared__ float red[8];
    __shared__ float a_sh[S_SZ];     // 8 KB
    const int sc  = blockIdx.x;      // 0..15
    const int b   = blockIdx.y;      // 0..31
    const int tid = threadIdx.x;

    // ---- softmax over S=2048 (redundant per block; e_part is L2-hot) ----
    float bv = b_v[0];
    float ev[8];
    float mx = -1e30f;
#pragma unroll
    for (int j = 0; j < 8; ++j) {
        int idx = b * S_SZ + j * 256 + tid;
        float e = bv;
#pragma unroll
        for (int p = 0; p < 8; ++p) e += e_part[(size_t)p * M_TOT + idx];
        e += mask[idx] * MASKED_BIAS;
        ev[j] = e;
        mx = fmaxf(mx, e);
    }
#pragma unroll
    for (int off = 32; off; off >>= 1) mx = fmaxf(mx, __shfl_xor(mx, off));
    if ((tid & 63) == 0) red[tid >> 6] = mx;
    __syncthreads();
    mx = fmaxf(fmaxf(red[0], red[1]), fmaxf(red[2], red[3]));
    float sum = 0.f;
#pragma unroll
    for (int j = 0; j < 8; ++j) { ev[j] = __expf(ev[j] - mx); sum += ev[j]; }
#pragma unroll
    for (int off = 32; off; off >>= 1) sum += __shfl_xor(sum, off);
    if ((tid & 63) == 0) red[4 + (tid >> 6)] = sum;
    __syncthreads();
    sum = red[4] + red[5] + red[6] + red[7];
    float inv = 1.f / sum;
#pragma unroll
    for (int j = 0; j < 8; ++j) {
        int s = j * 256 + tid;
        float a = ev[j] * inv;
        a_sh[s] = a;
        if (sc == 0) {
            int idx = b * S_SZ + s;
            a_out[idx]   = a;
            cov_out[idx] = cov[idx] + a;
        }
    }
    __syncthreads();

    // ---- context chunk: rows [sc*128, sc*128+128) ----
    const bf16* Kb = Kbf + ((size_t)b * S_SZ + sc * 128) * HIDDEN;
    const float* as = a_sh + sc * 128;
    float4 acc = {0.f, 0.f, 0.f, 0.f};
#pragma unroll 4
    for (int s = 0; s < 128; ++s) {
        float av = as[s];
        bf16x4 kv = *(const bf16x4*)(Kb + (size_t)s * HIDDEN + tid * 4);
        acc.x += av * (float)kv[0];
        acc.y += av * (float)kv[1];
        acc.z += av * (float)kv[2];
        acc.w += av * (float)kv[3];
    }
    ((float4*)part_out)[((size_t)b * 16 + sc) * 256 + tid] = acc;
}

// ---------------------------------------------------------------------------
// Kernel 5: out[b][h] = sum_sc part_out[b][sc][h]
// ---------------------------------------------------------------------------
__global__ __launch_bounds__(256) void k_ctx_reduce(
    const float* __restrict__ part_out, float* __restrict__ out, int nc)
{
    int b = blockIdx.x, tid = threadIdx.x;
    float4 acc = {0.f, 0.f, 0.f, 0.f};
    for (int sc = 0; sc < nc; ++sc) {
        float4 v = ((const float4*)part_out)[((size_t)b * nc + sc) * 256 + tid];
        acc.x += v.x; acc.y += v.y; acc.z += v.z; acc.w += v.w;
    }
    ((float4*)out)[b * 256 + tid] = acc;
}

// ---------------------------------------------------------------------------
extern "C" void kernel_launch(void* const* d_in, const int* in_sizes, int n_in,
                              void* d_out, int out_size, void* d_ws, size_t ws_size,
                              hipStream_t stream)
{
    const float* h     = (const float*)d_in[0];
    const float* Kin   = (const float*)d_in[1];
    const float* cov   = (const float*)d_in[2];
    const float* mask  = (const float*)d_in[3];
    const float* W_h   = (const float*)d_in[4];
    const float* b_h   = (const float*)d_in[5];
    const float* W_K   = (const float*)d_in[6];
    const float* b_K   = (const float*)d_in[7];
    const float* W_cov = (const float*)d_in[8];
    const float* b_cov = (const float*)d_in[9];
    const float* W_v   = (const float*)d_in[10];
    const float* b_v   = (const float*)d_in[11];

    float* out_ctx = (float*)d_out;            // 32*1024
    float* a_out   = out_ctx + B_SZ * HIDDEN;  // 32*2048
    float* cov_out = a_out + M_TOT;            // 32*2048

    float* ws       = (float*)d_ws;
    float* hl_plus  = ws;                        // 32768 f32
    float* e_part   = ws + 32768;                // 8*65536 f32 = 2 MB
    float* part_out = e_part;                    // alias (sequential: e_part
                                                 // fully read before part_out
                                                 // writes? NO -> use separate)
    // e_part is still being read by k_softctx while part_out is written by the
    // same kernel -> give part_out its own region after Bbf/Kbf are laid out.
    bf16*  Bbf      = (bf16*)(e_part + 8 * M_TOT);          // 2 MB
    bf16*  Kbf      = (bf16*)((char*)Bbf + (size_t)HIDDEN * HIDDEN * sizeof(bf16));
    float* part_sep = (float*)((char*)Kbf + (size_t)M_TOT * HIDDEN * sizeof(bf16));
    part_out = part_sep;                         // 32*16*1024 f32 = 2 MB

    k_prep<<<KCONV_BLKS + 512 + 512, 256, 0, stream>>>(
        Kin, Kbf, W_K, Bbf, h, W_h, b_h, b_K, b_cov, hl_plus);
    k_fused9<<<256 * NT_N, 512, 0, stream>>>(
        Kbf, Bbf, hl_plus, W_cov, cov, W_v, e_part);
    dim3 g3(16, B_SZ);
    k_softctx<<<g3, 256, 0, stream>>>(
        e_part, mask, cov, b_v, Kbf, a_out, cov_out, part_out);
    k_ctx_reduce<<<B_SZ, 256, 0, stream>>>(part_out, out_ctx, 16);
}